// Round 1
// 731.141 us; speedup vs baseline: 1.1447x; 1.1447x over previous
//
#include <hip/hip_runtime.h>
#include <stdint.h>

typedef __attribute__((ext_vector_type(8))) short short8;
typedef __attribute__((ext_vector_type(4))) float f32x4;

#define B_ 2
#define H_ 16
#define S_ 2048
#define D_ 64
#define KB_ 64
#define NT_ (S_ / KB_)   // 32 k-tiles

union PKU { unsigned u[4]; short8 s; };

// fp32 pair -> packed bf16x2 (round-half-up; differs from RNE only on exact ties)
__device__ __forceinline__ unsigned pk2(float x, float y) {
  const unsigned a = __builtin_bit_cast(unsigned, x) + 0x8000u;
  const unsigned b = __builtin_bit_cast(unsigned, y) + 0x8000u;
  return (a >> 16) | (b & 0xffff0000u);
}

__global__ __launch_bounds__(256, 4)
void attn_kernel(const float* __restrict__ Q, const float* __restrict__ K,
                 const float* __restrict__ V, const int* __restrict__ M,
                 float* __restrict__ O, float* __restrict__ A)
{
  // Bijective XCD-aware remap: consecutive dispatch ids round-robin the 8 XCDs;
  // give XCD x heads {x, x+8, x+16, x+24} (K/V of one head = 1MB -> L2-resident/XCD).
  const int bid = blockIdx.x + (blockIdx.y << 5);   // 0..1023
  const int qt  = (bid >> 3) & 31;                  // q-tile (64 rows)
  const int bh  = (bid & 7) | ((bid >> 8) << 3);    // b*H + h
  const int b   = bh >> 4;

  const int tid  = threadIdx.x;
  const int wave = tid >> 6;
  const int lane = tid & 63;
  const int l15  = lane & 15;
  const int quad = lane >> 4;

  const float* Qp = Q + (size_t)bh * S_ * D_;
  const float* Kp = K + (size_t)bh * S_ * D_;
  const float* Vp = V + (size_t)bh * S_ * D_;
  const int*   Mp = M + (size_t)b * S_ * S_;
  float* Op = O + (size_t)bh * S_ * D_;
  float* Ap = A + (size_t)bh * S_ * S_;

  const int q0 = qt * 64 + wave * 16;   // this wave's 16 q-rows

  // LDS (35840 B total -> 4 blocks/CU, grid-limited occupancy unchanged):
  //  Ks/Vt: row stride 72 shorts (144B) -> b128 frag reads at minimum bank aliasing.
  //  Ps: per-wave f32 score tile [16][68] (272B stride: float4-aligned, 2-way writes,
  //      conflict-free float4 reads). Pb (bf16 P for PV) aliases the wave's Ps slice.
  __shared__ __attribute__((aligned(16))) short Ks[64][72];
  __shared__ __attribute__((aligned(16))) short Vt[64][72];
  __shared__ __attribute__((aligned(16))) float Ps[4][16][68];
  short* Pb = (short*)&Ps[wave][0][0];   // [16][72] bf16, wave-private

  // Q A-fragments (m=lane&15, k=quad*8+j+32h), pre-scaled by 1/sqrt(D)=0.125 (exact)
  short8 aq[2];
  {
    const float* qr = Qp + (size_t)(q0 + l15) * D_ + quad * 8;
#pragma unroll
    for (int h = 0; h < 2; ++h) {
      const float4 x0 = *(const float4*)(qr + h * 32);
      const float4 x1 = *(const float4*)(qr + h * 32 + 4);
      PKU u;
      u.u[0] = pk2(x0.x * 0.125f, x0.y * 0.125f);
      u.u[1] = pk2(x0.z * 0.125f, x0.w * 0.125f);
      u.u[2] = pk2(x1.x * 0.125f, x1.y * 0.125f);
      u.u[3] = pk2(x1.z * 0.125f, x1.w * 0.125f);
      aq[h] = u.s;
    }
  }

  // staging assignments
  const int ksr  = tid >> 2;         // K row 0..63
  const int ksc  = (tid & 3) * 4;    // K col base; cols ksc+16j (64B/row segments)
  const int vd   = tid & 7;          // V d base; d = vd+8j  (consecutive-d per lane
  const int vk   = (tid >> 3) * 2;   // V kk pair            -> conflict-free Vt writes)
  const int lrow = lane >> 4;        // linear phase: rows lrow+4i
  const int lcol = (lane & 15) * 4;  //               cols lcol..lcol+3

  float kbuf[16];
  float vbuf[16];

  auto loadK = [&](int kt) {
#pragma unroll
    for (int j = 0; j < 4; ++j) {
      const float4 x = *(const float4*)(Kp + (size_t)(kt + ksr) * D_ + ksc + 16 * j);
      kbuf[4*j+0] = x.x; kbuf[4*j+1] = x.y; kbuf[4*j+2] = x.z; kbuf[4*j+3] = x.w;
    }
  };
  auto writeK = [&]() {
#pragma unroll
    for (int j = 0; j < 4; ++j)
      *(uint2*)&Ks[ksr][ksc + 16*j] =
        make_uint2(pk2(kbuf[4*j+0], kbuf[4*j+1]), pk2(kbuf[4*j+2], kbuf[4*j+3]));
  };
  auto loadV = [&](int kt) {
    const float* vr = Vp + (size_t)(kt + vk) * D_ + vd;
#pragma unroll
    for (int j = 0; j < 8; ++j) {
      vbuf[j]   = vr[8*j];        // V[kk  ][vd+8j]
      vbuf[8+j] = vr[D_ + 8*j];   // V[kk+1][vd+8j]
    }
  };
  auto writeV = [&]() {
#pragma unroll
    for (int j = 0; j < 8; ++j)   // consecutive d across lanes -> <=2-way banks
      *(unsigned*)&Vt[vd + 8*j][vk] = pk2(vbuf[j], vbuf[8+j]);
  };

  float lr[4];   // per-row -ln(denominator), carried in registers to pass 2

  // ---------------- pass 1: masked row sums ----------------
  {
    float rowsum[4] = {0.f, 0.f, 0.f, 0.f};
    loadK(0);
    writeK();
    __syncthreads();
    for (int t = 0; t < NT_; ++t) {
      const int kt = t * KB_;
      if (t + 1 < NT_) loadK(kt + KB_);          // prefetch next tile into regs
      int4 mr[4];
#pragma unroll
      for (int i = 0; i < 4; ++i)                // mask: coalesced int4, issued early
        mr[i] = *(const int4*)(Mp + (size_t)(q0 + lrow + 4*i) * S_ + kt + lcol);

      f32x4 acc[4] = {{0,0,0,0},{0,0,0,0},{0,0,0,0},{0,0,0,0}};
#pragma unroll
      for (int nt = 0; nt < 4; ++nt)
#pragma unroll
        for (int h = 0; h < 2; ++h) {
          const short8 bk = *(const short8*)&Ks[nt*16 + l15][h*32 + quad*8];
          acc[nt] = __builtin_amdgcn_mfma_f32_16x16x32_bf16(aq[h], bk, acc[nt], 0, 0, 0);
        }
      // C-layout -> LDS, read back linearly
#pragma unroll
      for (int nt = 0; nt < 4; ++nt)
#pragma unroll
        for (int r = 0; r < 4; ++r)
          Ps[wave][quad*4 + r][nt*16 + l15] = acc[nt][r];
      __asm__ volatile("s_waitcnt lgkmcnt(0)" ::: "memory");
#pragma unroll
      for (int i = 0; i < 4; ++i) {
        const f32x4 s = *(const f32x4*)&Ps[wave][lrow + 4*i][lcol];
        const float e0 = mr[i].x ? __expf(s[0]) : 0.f;
        const float e1 = mr[i].y ? __expf(s[1]) : 0.f;
        const float e2 = mr[i].z ? __expf(s[2]) : 0.f;
        const float e3 = mr[i].w ? __expf(s[3]) : 0.f;
        rowsum[i] += (e0 + e1) + (e2 + e3);
      }
      __syncthreads();                            // all waves done reading Ks[t]
      if (t + 1 < NT_) writeK();                  // convert + write t+1
      __syncthreads();
    }
    // sum the 16 col-lanes of each row; keep -ln(sum) (guard all-masked rows)
#pragma unroll
    for (int i = 0; i < 4; ++i) {
      float s = rowsum[i];
      s += __shfl_xor(s, 1);
      s += __shfl_xor(s, 2);
      s += __shfl_xor(s, 4);
      s += __shfl_xor(s, 8);
      lr[i] = (s > 0.f) ? -__logf(s) : 0.f;
    }
  }

  // ---------------- pass 2: attn write + PV ----------------
  f32x4 oacc[4] = {{0,0,0,0},{0,0,0,0},{0,0,0,0},{0,0,0,0}};
  loadK(0);
  loadV(0);
  writeK();          // safe: pass-1 trailing barrier already drained all Ks readers
  writeV();
  __syncthreads();
  for (int t = 0; t < NT_; ++t) {
    const int kt = t * KB_;
    if (t + 1 < NT_) { loadK(kt + KB_); loadV(kt + KB_); }
    int4 mr[4];
#pragma unroll
    for (int i = 0; i < 4; ++i)
      mr[i] = *(const int4*)(Mp + (size_t)(q0 + lrow + 4*i) * S_ + kt + lcol);

    f32x4 acc[4] = {{0,0,0,0},{0,0,0,0},{0,0,0,0},{0,0,0,0}};
#pragma unroll
    for (int nt = 0; nt < 4; ++nt)
#pragma unroll
      for (int h = 0; h < 2; ++h) {
        const short8 bk = *(const short8*)&Ks[nt*16 + l15][h*32 + quad*8];
        acc[nt] = __builtin_amdgcn_mfma_f32_16x16x32_bf16(aq[h], bk, acc[nt], 0, 0, 0);
      }
#pragma unroll
    for (int nt = 0; nt < 4; ++nt)
#pragma unroll
      for (int r = 0; r < 4; ++r)
        Ps[wave][quad*4 + r][nt*16 + l15] = acc[nt][r];
    __asm__ volatile("s_waitcnt lgkmcnt(0)" ::: "memory");

    f32x4 sr[4];
#pragma unroll
    for (int i = 0; i < 4; ++i)
      sr[i] = *(const f32x4*)&Ps[wave][lrow + 4*i][lcol];
    // all f32 reads landed before Pb (aliased) is overwritten
    __asm__ volatile("s_waitcnt lgkmcnt(0)" ::: "memory");

#pragma unroll
    for (int i = 0; i < 4; ++i) {
      const float lv = lr[i];
      f32x4 p;
      p[0] = __expf(mr[i].x ? sr[i][0] + lv : -1e5f);   // exp(s - ln l); masked -> 0
      p[1] = __expf(mr[i].y ? sr[i][1] + lv : -1e5f);
      p[2] = __expf(mr[i].z ? sr[i][2] + lv : -1e5f);
      p[3] = __expf(mr[i].w ? sr[i][3] + lv : -1e5f);
      __builtin_nontemporal_store(p, (f32x4*)(Ap + (size_t)(q0 + lrow + 4*i) * S_ + kt + lcol));
      *(uint2*)&Pb[(lrow + 4*i) * 72 + lcol] =
        make_uint2(pk2(p[0], p[1]), pk2(p[2], p[3]));
    }
    __asm__ volatile("s_waitcnt lgkmcnt(0)" ::: "memory");

    // PV: A-frag from Pb (m=l15, k=quad*8+j+32h'), B-frag from Vt
    const short8 pa0 = *(const short8*)&Pb[l15 * 72 + quad * 8];
    const short8 pa1 = *(const short8*)&Pb[l15 * 72 + 32 + quad * 8];
#pragma unroll
    for (int nt = 0; nt < 4; ++nt) {
      const short8 bv0 = *(const short8*)&Vt[nt*16 + l15][quad*8];
      const short8 bv1 = *(const short8*)&Vt[nt*16 + l15][32 + quad*8];
      oacc[nt] = __builtin_amdgcn_mfma_f32_16x16x32_bf16(pa0, bv0, oacc[nt], 0, 0, 0);
      oacc[nt] = __builtin_amdgcn_mfma_f32_16x16x32_bf16(pa1, bv1, oacc[nt], 0, 0, 0);
    }
    __syncthreads();
    if (t + 1 < NT_) { writeK(); writeV(); }
    __syncthreads();
  }

  // epilogue: O tile (C/D layout), 16-lane coalesced
#pragma unroll
  for (int nt = 0; nt < 4; ++nt)
#pragma unroll
    for (int r = 0; r < 4; ++r)
      Op[(size_t)(q0 + quad*4 + r) * D_ + nt*16 + l15] = oacc[nt][r];
}

extern "C" void kernel_launch(void* const* d_in, const int* in_sizes, int n_in,
                              void* d_out, int out_size, void* d_ws, size_t ws_size,
                              hipStream_t stream) {
  const float* q = (const float*)d_in[0];
  const float* k = (const float*)d_in[1];
  const float* v = (const float*)d_in[2];
  const int*   m = (const int*)d_in[3];
  float* out  = (float*)d_out;
  float* attn = out + (size_t)B_ * H_ * S_ * D_;   // tuple order: (out, attn)

  dim3 grid(S_ / 64, B_ * H_);
  attn_kernel<<<grid, 256, 0, stream>>>(q, k, v, m, out, attn);
}